// Round 5
// baseline (162.278 us; speedup 1.0000x reference)
//
#include <hip/hip_runtime.h>
#include <math.h>

#define BB 4096
#define HH 512
#define KK 32
#define PAIRS ((KK * (KK - 1)) / 2)   // 496

constexpr int TH  = 16;              // h-values per stage1 job
constexpr int NBB = 8;               // B-chunks
constexpr int BC  = BB / NBB;        // 512 rows per stage1 job
constexpr int SUB = 64;              // rows staged in LDS at a time
constexpr int RP  = TH + 1;          // padded reduce stride (17)
constexpr int S1B = (HH / TH) * NBB; // 256 stage1 jobs
constexpr unsigned MAGIC = 0x5F17BEEFu;

// ---------------------------------------------------------------------------
// Exact t-CDF series coefficients (A&S 26.7.3/4), compile-time tables.
//   even nu: A = sqrt(x) * sum ce[j]*(1-x)^j          ce[j]=prod (2i-1)/(2i)
//   odd  nu: A = 2/pi*(theta + sqrt(x(1-x))*sum co[j]*(1-x)^j), co[j]=prod (2i)/(2i+1)
// ---------------------------------------------------------------------------
struct TabE {
    float v[2048];
    constexpr TabE() : v{} {
        double c = 1.0; v[0] = 1.0f;
        for (int j = 1; j < 2048; ++j) { c *= (2.0*j - 1.0) / (2.0*j); v[j] = (float)c; }
    }
};
struct TabO {
    float v[2048];
    constexpr TabO() : v{} {
        double c = 1.0; v[0] = 1.0f;
        for (int j = 1; j < 2048; ++j) { c *= (2.0*j) / (2.0*j + 1.0); v[j] = (float)c; }
    }
};
__device__ constexpr TabE tab_e{};
__device__ constexpr TabO tab_o{};

__device__ __forceinline__ float frcp(float x) {
#if __has_builtin(__builtin_amdgcn_rcpf)
    return __builtin_amdgcn_rcpf(x);
#else
    return 1.0f / x;
#endif
}
__device__ __forceinline__ float guardf(float t) {
    return (fabsf(t) < 1e-30f) ? 1e-30f : t;
}

// NR betacf fallback (only for non-integer d2 — never taken with this data)
__device__ float betacf_fast(float a, float b, float x)
{
    const float EPS = 1e-5f;
    float qab = a + b, qap = a + 1.0f, qam = a - 1.0f;
    float c = 1.0f;
    float d = frcp(guardf(1.0f - qab * x * frcp(qap)));
    float h = d;
    for (int m = 1; m <= 100; ++m) {
        float fm = (float)m, m2 = 2.0f * fm;
        float aa = fm * (b - fm) * x * frcp((qam + m2) * (a + m2));
        d = frcp(guardf(fmaf(aa, d, 1.0f)));
        c = guardf(fmaf(aa, frcp(c), 1.0f));
        h *= d * c;
        float aa2 = -(a + fm) * (qab + fm) * x * frcp((a + m2) * (qap + m2));
        d = frcp(guardf(fmaf(aa2, d, 1.0f)));
        c = guardf(fmaf(aa2, frcp(c), 1.0f));
        float del = d * c;
        h *= del;
        if (__all(fabsf(del - 1.0f) < EPS)) break;
    }
    return h;
}

// ---------------------------------------------------------------------------
// Fused kernel, 496 blocks x 256 threads.
// Phase A (blocks < 256): stage1 partials, chunk c = bid>>5, h-tile hx = bid&31.
// Phase B: flag spin (poison-proof magic flags, release/acquire).
// Phase C (all 496): one pair per block; deterministic final sum by last block.
// ---------------------------------------------------------------------------
__global__ __launch_bounds__(256) void fused_kernel(
    const float* __restrict__ hidden, const float* __restrict__ cluster,
    float* __restrict__ part_m, float* __restrict__ part_s,
    float* __restrict__ pcol, float* __restrict__ pres,
    unsigned* __restrict__ pctr, unsigned* __restrict__ flags,
    const int* __restrict__ dptr, float* __restrict__ out)
{
    __shared__ float hid_s [SUB * TH];
    __shared__ float hid2_s[SUB * TH];
    __shared__ float clu_s [SUB * KK];
    __shared__ float red   [8 * KK * RP];
    __shared__ float cred  [8 * KK];
    __shared__ float xs[HH];

    const int t   = threadIdx.x;
    const int bid = blockIdx.x;

    // ---------------- Phase A: stage1 ----------------
    if (bid < S1B) {
        const int ty = t >> 5;
        const int tx = t & 31;
        const int hx = bid & 31;
        const int c  = bid >> 5;
        const int h0 = hx * TH;
        const int bchunk = c * BC;

        if (bid == 0 && t == 0) *pctr = 0u;   // visible via flag[0] release

        float acc_m[TH], acc_s[TH];
#pragma unroll
        for (int i = 0; i < TH; ++i) { acc_m[i] = 0.f; acc_s[i] = 0.f; }
        float csum = 0.f;

        const float4* hid4 = (const float4*)hidden;
        const float4* clu4 = (const float4*)cluster;

        for (int sub = 0; sub < BC; sub += SUB) {
            const int b0 = bchunk + sub;
            {   // hidden tile: 64 rows x 16 cols = 256 float4; squares at load
                int r = t >> 2, q = t & 3;
                float4 v = hid4[(size_t)(b0 + r) * (HH / 4) + (h0 >> 2) + q];
                ((float4*)hid_s)[t] = v;
                float4 v2; v2.x=v.x*v.x; v2.y=v.y*v.y; v2.z=v.z*v.z; v2.w=v.w*v.w;
                ((float4*)hid2_s)[t] = v2;
            }
#pragma unroll
            for (int e = 0; e < 2; ++e) {      // cluster tile: 512 float4
                int u = t + e * 256;
                int r = u >> 3, q = u & 7;
                ((float4*)clu_s)[u] = clu4[(size_t)(b0 + r) * (KK / 4) + q];
            }
            __syncthreads();

            const float4* h4 = (const float4*)hid_s;
            const float4* g4 = (const float4*)hid2_s;
#pragma unroll
            for (int s = 0; s < SUB / 8; ++s) {
                int r = s * 8 + ty;
                float cc = clu_s[r * KK + tx];
                float c2 = cc * cc;
                csum += cc;
                float4 a0=h4[r*4+0], a1=h4[r*4+1], a2=h4[r*4+2], a3=h4[r*4+3];
                float4 q0=g4[r*4+0], q1=g4[r*4+1], q2=g4[r*4+2], q3=g4[r*4+3];
                acc_m[0] =fmaf(a0.x,cc,acc_m[0]);  acc_m[1] =fmaf(a0.y,cc,acc_m[1]);
                acc_m[2] =fmaf(a0.z,cc,acc_m[2]);  acc_m[3] =fmaf(a0.w,cc,acc_m[3]);
                acc_m[4] =fmaf(a1.x,cc,acc_m[4]);  acc_m[5] =fmaf(a1.y,cc,acc_m[5]);
                acc_m[6] =fmaf(a1.z,cc,acc_m[6]);  acc_m[7] =fmaf(a1.w,cc,acc_m[7]);
                acc_m[8] =fmaf(a2.x,cc,acc_m[8]);  acc_m[9] =fmaf(a2.y,cc,acc_m[9]);
                acc_m[10]=fmaf(a2.z,cc,acc_m[10]); acc_m[11]=fmaf(a2.w,cc,acc_m[11]);
                acc_m[12]=fmaf(a3.x,cc,acc_m[12]); acc_m[13]=fmaf(a3.y,cc,acc_m[13]);
                acc_m[14]=fmaf(a3.z,cc,acc_m[14]); acc_m[15]=fmaf(a3.w,cc,acc_m[15]);
                acc_s[0] =fmaf(q0.x,c2,acc_s[0]);  acc_s[1] =fmaf(q0.y,c2,acc_s[1]);
                acc_s[2] =fmaf(q0.z,c2,acc_s[2]);  acc_s[3] =fmaf(q0.w,c2,acc_s[3]);
                acc_s[4] =fmaf(q1.x,c2,acc_s[4]);  acc_s[5] =fmaf(q1.y,c2,acc_s[5]);
                acc_s[6] =fmaf(q1.z,c2,acc_s[6]);  acc_s[7] =fmaf(q1.w,c2,acc_s[7]);
                acc_s[8] =fmaf(q2.x,c2,acc_s[8]);  acc_s[9] =fmaf(q2.y,c2,acc_s[9]);
                acc_s[10]=fmaf(q2.z,c2,acc_s[10]); acc_s[11]=fmaf(q2.w,c2,acc_s[11]);
                acc_s[12]=fmaf(q3.x,c2,acc_s[12]); acc_s[13]=fmaf(q3.y,c2,acc_s[13]);
                acc_s[14]=fmaf(q3.z,c2,acc_s[14]); acc_s[15]=fmaf(q3.w,c2,acc_s[15]);
            }
            __syncthreads();
        }

        cred[ty * KK + tx] = csum;
        __syncthreads();
        if (hx == 0 && t < KK) {
            float v = 0.f;
#pragma unroll
            for (int g = 0; g < 8; ++g) v += cred[g * KK + t];
            pcol[c * KK + t] = v;
        }

#pragma unroll
        for (int hh = 0; hh < TH; ++hh)
            red[ty * (KK * RP) + tx * RP + hh] = acc_m[hh];
        __syncthreads();
        for (int u = t; u < KK * TH; u += 256) {
            int k = u >> 4, hh = u & 15;
            float v = 0.f;
#pragma unroll
            for (int g = 0; g < 8; ++g) v += red[g * (KK * RP) + k * RP + hh];
            part_m[((size_t)c * KK + k) * HH + h0 + hh] = v;
        }
        __syncthreads();
#pragma unroll
        for (int hh = 0; hh < TH; ++hh)
            red[ty * (KK * RP) + tx * RP + hh] = acc_s[hh];
        __syncthreads();
        for (int u = t; u < KK * TH; u += 256) {
            int k = u >> 4, hh = u & 15;
            float v = 0.f;
#pragma unroll
            for (int g = 0; g < 8; ++g) v += red[g * (KK * RP) + k * RP + hh];
            part_s[((size_t)c * KK + k) * HH + h0 + hh] = v;
        }

        // publish: canonical fence-all + barrier + release flag
        __threadfence();
        __syncthreads();
        if (t == 0)
            __hip_atomic_store(&flags[bid], MAGIC, __ATOMIC_RELEASE,
                               __HIP_MEMORY_SCOPE_AGENT);
    }

    // ---------------- Phase B: wait for all 256 stage1 flags ----------------
    // Each thread polls one flag (relaxed), then one acquire fence.
    while (__hip_atomic_load(&flags[t], __ATOMIC_RELAXED,
                             __HIP_MEMORY_SCOPE_AGENT) != MAGIC)
        __builtin_amdgcn_s_sleep(2);
    __threadfence();
    __syncthreads();

    // ---------------- Phase C: one pair per block ----------------
    const int w = t >> 6, lane = t & 63;
    const int p = bid;

    int i = 0, rem = p;
    while (true) { int row = KK - 1 - i; if (rem < row) break; rem -= row; ++i; }
    const int j = i + 1 + rem;

    float ci = 0.f, cj = 0.f;
#pragma unroll
    for (int cc = 0; cc < NBB; ++cc) {
        ci += pcol[cc * KK + i];
        cj += pcol[cc * KK + j];
    }
    ci = roundf(ci); cj = roundf(cj);
    const float pc = ci + cj;
    float d2 = pc - 2.0f;
    if (d2 == 0.0f) d2 = 1e-5f;
    const float b = 0.5f * d2;

#pragma unroll
    for (int q = 0; q < 2; ++q) {
        int h = w * 128 + q * 64 + lane;
        float mi = 0.f, mj = 0.f, si = 0.f, sj = 0.f;
#pragma unroll
        for (int cc = 0; cc < NBB; ++cc) {
            size_t base = (size_t)cc * KK * HH;
            mi += part_m[base + (size_t)i * HH + h];
            mj += part_m[base + (size_t)j * HH + h];
            si += part_s[base + (size_t)i * HH + h];
            sj += part_s[base + (size_t)j * HH + h];
        }
        float wi = fmaf((float)(BB - 2) * mi, mi, si);
        float wj = fmaf((float)(BB - 2) * mj, mj, sj);
        float dm = 0.5f * (mi - mj);
        float between = dm * dm * pc;
        float denom = between + wi + wj;
        float x = between / denom;
        if (!(x >= 1e-37f)) x = 1e-37f;       // also catches NaN
        x = fminf(x, 1.0f - 1e-5f);
        xs[h] = x;
    }
    __syncthreads();
    if (w != 0) return;

    // ---- wave 0: top-d of x (betainc monotone in x for fixed a,b) ----
    float lv[8];
#pragma unroll
    for (int q = 0; q < 8; ++q) lv[q] = xs[q * 64 + lane];

    const int d = *dptr;
    float myx = 0.004f;
    float lm = lv[0];
#pragma unroll
    for (int q = 1; q < 8; ++q) lm = fmaxf(lm, lv[q]);

    for (int r = 0; r < d; ++r) {
        float gm = lm;
#pragma unroll
        for (int off = 1; off < 64; off <<= 1)
            gm = fmaxf(gm, __shfl_xor(gm, off));
        unsigned long long msk = __ballot(lm == gm);
        int winner = __ffsll((unsigned long long)msk) - 1;
        if (lane == r) myx = gm;
        if (lane == winner) {
            bool done = false;
#pragma unroll
            for (int q = 0; q < 8; ++q)
                if (!done && lv[q] == gm) { lv[q] = -1.0f; done = true; }
            lm = lv[0];
#pragma unroll
            for (int q = 1; q < 8; ++q) lm = fmaxf(lm, lv[q]);
        }
    }

    // ---- d parallel betainc evals: exact finite series for integer dof ----
    float x  = myx;
    float u  = 1.0f - x;
    float sx = sqrtf(x);
    int nu = (int)(d2 + 0.5f);
    float L;
    if (nu >= 1 && nu <= 4094 && fabsf(d2 - (float)nu) < 1e-3f) {
        float u2 = u * u;
        if (nu & 1) {
            int terms = (nu - 1) >> 1;
            float S = 0.f;
            if (terms > 0) {
                float S0 = 0.f, S1 = 0.f, p0 = 1.f, p1 = u;
                int jj = 0;
                for (; jj + 1 < terms; jj += 2) {
                    S0 = fmaf(tab_o.v[jj],     p0, S0);
                    S1 = fmaf(tab_o.v[jj + 1], p1, S1);
                    p0 *= u2; p1 *= u2;
                }
                if (jj < terms) S0 = fmaf(tab_o.v[jj], p0, S0);
                S = S0 + S1;
            }
            float theta = asinf(fminf(sx, 1.0f));
            float A = 0.636619772367581343f * (theta + sx * sqrtf(u) * S);
            L = logf(fminf(A, 1.0f));
        } else {
            int terms = nu >> 1;
            float S0 = 0.f, S1 = 0.f, p0 = 1.f, p1 = u;
            int jj = 0;
            for (; jj + 1 < terms; jj += 2) {
                S0 = fmaf(tab_e.v[jj],     p0, S0);
                S1 = fmaf(tab_e.v[jj + 1], p1, S1);
                p0 *= u2; p1 *= u2;
            }
            if (jj < terms) S0 = fmaf(tab_e.v[jj], p0, S0);
            float A = sx * (S0 + S1);
            L = logf(fminf(A, 1.0f));
        }
    } else {
        const float a = 0.5f;
        const float lg = lgammaf(a + b) - lgammaf(b) - 0.57236494f;
        const float xsplit = (a + 1.0f) / (a + b + 2.0f);
        bool  brA = x < xsplit;
        float al  = brA ? a : b;
        float be  = brA ? b : a;
        float xx  = brA ? x : u;
        float cf  = betacf_fast(al, be, xx);
        float lbt = lg + 0.5f * logf(x) + b * logf(u);
        if (brA) {
            L = lbt + logf(2.0f * fmaxf(cf, 1e-30f));
        } else {
            float tt = expf(lbt) * cf / b;
            tt = fminf(tt, 0.99999988f);
            L = log1pf(-tt);
        }
    }

    float val = (lane < d) ? L : 0.0f;
#pragma unroll
    for (int off = 1; off < 64; off <<= 1) val += __shfl_xor(val, off);

    // per-pair result -> pres[p]; last block does the deterministic sum
    unsigned old = 0u;
    if (lane == 0) {
        pres[p] = val;
        __threadfence();
        old = __hip_atomic_fetch_add(pctr, 1u, __ATOMIC_ACQ_REL,
                                     __HIP_MEMORY_SCOPE_AGENT);
    }
    old = __shfl(old, 0);
    if (old == PAIRS - 1) {
        __threadfence();
        float s = 0.f;
#pragma unroll
        for (int q = 0; q < 8; ++q) {
            int idx = q * 64 + lane;
            if (idx < PAIRS)
                s += __hip_atomic_load(&pres[idx], __ATOMIC_ACQUIRE,
                                       __HIP_MEMORY_SCOPE_AGENT);
        }
#pragma unroll
        for (int off = 1; off < 64; off <<= 1) s += __shfl_xor(s, off);
        if (lane == 0) out[0] = -s;
    }
}

// ---------------------------------------------------------------------------
extern "C" void kernel_launch(void* const* d_in, const int* in_sizes, int n_in,
                              void* d_out, int out_size, void* d_ws, size_t ws_size,
                              hipStream_t stream)
{
    const float* hidden  = (const float*)d_in[0];
    const float* cluster = (const float*)d_in[1];
    const int*   dptr    = (const int*)d_in[2];

    float*    part_m = (float*)d_ws;                     // [NBB][KK][HH]
    float*    part_s = part_m + (size_t)NBB * KK * HH;   // [NBB][KK][HH]
    float*    pcol   = part_s + (size_t)NBB * KK * HH;   // [NBB][KK]
    float*    pres   = pcol + NBB * KK;                  // [PAIRS]
    unsigned* pctr   = (unsigned*)(pres + PAIRS);        // 1
    unsigned* flags  = pctr + 1;                         // [S1B]

    fused_kernel<<<PAIRS, 256, 0, stream>>>(hidden, cluster,
                                            part_m, part_s, pcol, pres,
                                            pctr, flags, dptr, (float*)d_out);
}

// Round 6
// 152.294 us; speedup vs baseline: 1.0656x; 1.0656x over previous
//
#include <hip/hip_runtime.h>
#include <math.h>

#define BB 4096
#define HH 512
#define KK 32
#define PAIRS ((KK * (KK - 1)) / 2)   // 496

constexpr int TH   = 16;             // h-values per stage1 job
constexpr int NBB  = 8;              // B-chunks
constexpr int BC   = BB / NBB;       // 512 rows per stage1 job
constexpr int SUB  = 64;             // rows staged in LDS at a time
constexpr int RP   = TH + 1;         // padded reduce stride (17)
constexpr int GRID = (HH / TH) * NBB; // 256 blocks, all producers

// ---------------------------------------------------------------------------
// Exact t-CDF series coefficients (A&S 26.7.3/4), compile-time tables.
// ---------------------------------------------------------------------------
struct TabE {
    float v[2048];
    constexpr TabE() : v{} {
        double c = 1.0; v[0] = 1.0f;
        for (int j = 1; j < 2048; ++j) { c *= (2.0*j - 1.0) / (2.0*j); v[j] = (float)c; }
    }
};
struct TabO {
    float v[2048];
    constexpr TabO() : v{} {
        double c = 1.0; v[0] = 1.0f;
        for (int j = 1; j < 2048; ++j) { c *= (2.0*j) / (2.0*j + 1.0); v[j] = (float)c; }
    }
};
__device__ constexpr TabE tab_e{};
__device__ constexpr TabO tab_o{};

__device__ __forceinline__ float frcp(float x) {
#if __has_builtin(__builtin_amdgcn_rcpf)
    return __builtin_amdgcn_rcpf(x);
#else
    return 1.0f / x;
#endif
}
__device__ __forceinline__ float guardf(float t) {
    return (fabsf(t) < 1e-30f) ? 1e-30f : t;
}

// NR betacf fallback (only for non-integer d2 — never taken with this data)
__device__ float betacf_fast(float a, float b, float x)
{
    const float EPS = 1e-5f;
    float qab = a + b, qap = a + 1.0f, qam = a - 1.0f;
    float c = 1.0f;
    float d = frcp(guardf(1.0f - qab * x * frcp(qap)));
    float h = d;
    for (int m = 1; m <= 100; ++m) {
        float fm = (float)m, m2 = 2.0f * fm;
        float aa = fm * (b - fm) * x * frcp((qam + m2) * (a + m2));
        d = frcp(guardf(fmaf(aa, d, 1.0f)));
        c = guardf(fmaf(aa, frcp(c), 1.0f));
        h *= d * c;
        float aa2 = -(a + fm) * (qab + fm) * x * frcp((a + m2) * (qap + m2));
        d = frcp(guardf(fmaf(aa2, d, 1.0f)));
        c = guardf(fmaf(aa2, frcp(c), 1.0f));
        float del = d * c;
        h *= del;
        if (__all(fabsf(del - 1.0f) < EPS)) break;
    }
    return h;
}

// ---------------------------------------------------------------------------
// Fused kernel, 256 blocks x 256 threads (all blocks are producers).
// Phase A: stage1 partials (chunk c = bid>>5, h-tile hx = bid&31).
// Phase B: single-counter grid sync — ONE poller per block, 1k-cyc backoff.
// Phase C: one pair per WAVE (p = w*256 + bid); x in registers, no barriers.
// ---------------------------------------------------------------------------
__global__ __launch_bounds__(256) void fused_kernel(
    const float* __restrict__ hidden, const float* __restrict__ cluster,
    float* __restrict__ part_m, float* __restrict__ part_s,
    float* __restrict__ pcol, float* __restrict__ pres,
    unsigned* __restrict__ ctrs,     // [0]=sync counter, [1]=pair counter (pre-zeroed)
    const int* __restrict__ dptr, float* __restrict__ out)
{
    __shared__ float hid_s [SUB * TH];
    __shared__ float hid2_s[SUB * TH];
    __shared__ float clu_s [SUB * KK];
    __shared__ float red   [8 * KK * RP];
    __shared__ float cred  [8 * KK];

    const int t   = threadIdx.x;
    const int bid = blockIdx.x;

    // ---------------- Phase A: stage1 ----------------
    {
        const int ty = t >> 5;
        const int tx = t & 31;
        const int hx = bid & 31;
        const int c  = bid >> 5;
        const int h0 = hx * TH;
        const int bchunk = c * BC;

        float acc_m[TH], acc_s[TH];
#pragma unroll
        for (int i = 0; i < TH; ++i) { acc_m[i] = 0.f; acc_s[i] = 0.f; }
        float csum = 0.f;

        const float4* hid4 = (const float4*)hidden;
        const float4* clu4 = (const float4*)cluster;

        for (int sub = 0; sub < BC; sub += SUB) {
            const int b0 = bchunk + sub;
            {   // hidden tile: 64 rows x 16 cols = 256 float4; squares at load
                int r = t >> 2, q = t & 3;
                float4 v = hid4[(size_t)(b0 + r) * (HH / 4) + (h0 >> 2) + q];
                ((float4*)hid_s)[t] = v;
                float4 v2; v2.x=v.x*v.x; v2.y=v.y*v.y; v2.z=v.z*v.z; v2.w=v.w*v.w;
                ((float4*)hid2_s)[t] = v2;
            }
#pragma unroll
            for (int e = 0; e < 2; ++e) {      // cluster tile: 512 float4
                int u = t + e * 256;
                int r = u >> 3, q = u & 7;
                ((float4*)clu_s)[u] = clu4[(size_t)(b0 + r) * (KK / 4) + q];
            }
            __syncthreads();

            const float4* h4 = (const float4*)hid_s;
            const float4* g4 = (const float4*)hid2_s;
#pragma unroll
            for (int s = 0; s < SUB / 8; ++s) {
                int r = s * 8 + ty;
                float cc = clu_s[r * KK + tx];
                float c2 = cc * cc;
                csum += cc;
                float4 a0=h4[r*4+0], a1=h4[r*4+1], a2=h4[r*4+2], a3=h4[r*4+3];
                float4 q0=g4[r*4+0], q1=g4[r*4+1], q2=g4[r*4+2], q3=g4[r*4+3];
                acc_m[0] =fmaf(a0.x,cc,acc_m[0]);  acc_m[1] =fmaf(a0.y,cc,acc_m[1]);
                acc_m[2] =fmaf(a0.z,cc,acc_m[2]);  acc_m[3] =fmaf(a0.w,cc,acc_m[3]);
                acc_m[4] =fmaf(a1.x,cc,acc_m[4]);  acc_m[5] =fmaf(a1.y,cc,acc_m[5]);
                acc_m[6] =fmaf(a1.z,cc,acc_m[6]);  acc_m[7] =fmaf(a1.w,cc,acc_m[7]);
                acc_m[8] =fmaf(a2.x,cc,acc_m[8]);  acc_m[9] =fmaf(a2.y,cc,acc_m[9]);
                acc_m[10]=fmaf(a2.z,cc,acc_m[10]); acc_m[11]=fmaf(a2.w,cc,acc_m[11]);
                acc_m[12]=fmaf(a3.x,cc,acc_m[12]); acc_m[13]=fmaf(a3.y,cc,acc_m[13]);
                acc_m[14]=fmaf(a3.z,cc,acc_m[14]); acc_m[15]=fmaf(a3.w,cc,acc_m[15]);
                acc_s[0] =fmaf(q0.x,c2,acc_s[0]);  acc_s[1] =fmaf(q0.y,c2,acc_s[1]);
                acc_s[2] =fmaf(q0.z,c2,acc_s[2]);  acc_s[3] =fmaf(q0.w,c2,acc_s[3]);
                acc_s[4] =fmaf(q1.x,c2,acc_s[4]);  acc_s[5] =fmaf(q1.y,c2,acc_s[5]);
                acc_s[6] =fmaf(q1.z,c2,acc_s[6]);  acc_s[7] =fmaf(q1.w,c2,acc_s[7]);
                acc_s[8] =fmaf(q2.x,c2,acc_s[8]);  acc_s[9] =fmaf(q2.y,c2,acc_s[9]);
                acc_s[10]=fmaf(q2.z,c2,acc_s[10]); acc_s[11]=fmaf(q2.w,c2,acc_s[11]);
                acc_s[12]=fmaf(q3.x,c2,acc_s[12]); acc_s[13]=fmaf(q3.y,c2,acc_s[13]);
                acc_s[14]=fmaf(q3.z,c2,acc_s[14]); acc_s[15]=fmaf(q3.w,c2,acc_s[15]);
            }
            __syncthreads();
        }

        cred[ty * KK + tx] = csum;
        __syncthreads();
        if (hx == 0 && t < KK) {
            float v = 0.f;
#pragma unroll
            for (int g = 0; g < 8; ++g) v += cred[g * KK + t];
            pcol[c * KK + t] = v;
        }

#pragma unroll
        for (int hh = 0; hh < TH; ++hh)
            red[ty * (KK * RP) + tx * RP + hh] = acc_m[hh];
        __syncthreads();
        for (int u = t; u < KK * TH; u += 256) {
            int k = u >> 4, hh = u & 15;
            float v = 0.f;
#pragma unroll
            for (int g = 0; g < 8; ++g) v += red[g * (KK * RP) + k * RP + hh];
            part_m[((size_t)c * KK + k) * HH + h0 + hh] = v;
        }
        __syncthreads();
#pragma unroll
        for (int hh = 0; hh < TH; ++hh)
            red[ty * (KK * RP) + tx * RP + hh] = acc_s[hh];
        __syncthreads();
        for (int u = t; u < KK * TH; u += 256) {
            int k = u >> 4, hh = u & 15;
            float v = 0.f;
#pragma unroll
            for (int g = 0; g < 8; ++g) v += red[g * (KK * RP) + k * RP + hh];
            part_s[((size_t)c * KK + k) * HH + h0 + hh] = v;
        }
    }

    // ---------------- Phase B: light grid sync ----------------
    // Publish: fence + barrier, then ONE release-add per block.
    // Wait: ONE poller per block on ONE cache line, ~1k-cycle backoff.
    __threadfence();
    __syncthreads();
    if (t == 0) {
        __hip_atomic_fetch_add(&ctrs[0], 1u, __ATOMIC_RELEASE,
                               __HIP_MEMORY_SCOPE_AGENT);
        while (__hip_atomic_load(&ctrs[0], __ATOMIC_RELAXED,
                                 __HIP_MEMORY_SCOPE_AGENT) != (unsigned)GRID)
            __builtin_amdgcn_s_sleep(16);
    }
    __syncthreads();
    __threadfence();   // acquire: invalidate stale cached partials

    // ---------------- Phase C: one pair per wave ----------------
    const int w = t >> 6, lane = t & 63;
    const int p = w * GRID + bid;
    if (p >= PAIRS) return;               // wave-uniform exit

    int i = 0, rem = p;
    while (true) { int row = KK - 1 - i; if (rem < row) break; rem -= row; ++i; }
    const int j = i + 1 + rem;

    float ci = 0.f, cj = 0.f;
#pragma unroll
    for (int cc = 0; cc < NBB; ++cc) {
        ci += pcol[cc * KK + i];
        cj += pcol[cc * KK + j];
    }
    ci = roundf(ci); cj = roundf(cj);
    const float pc = ci + cj;
    float d2 = pc - 2.0f;
    if (d2 == 0.0f) d2 = 1e-5f;
    const float b = 0.5f * d2;

    float lv[8];
#pragma unroll
    for (int q = 0; q < 8; ++q) {
        int h = q * 64 + lane;
        float mi = 0.f, mj = 0.f, si = 0.f, sj = 0.f;
#pragma unroll
        for (int cc = 0; cc < NBB; ++cc) {
            size_t base = (size_t)cc * KK * HH;
            mi += part_m[base + (size_t)i * HH + h];
            mj += part_m[base + (size_t)j * HH + h];
            si += part_s[base + (size_t)i * HH + h];
            sj += part_s[base + (size_t)j * HH + h];
        }
        float wi = fmaf((float)(BB - 2) * mi, mi, si);
        float wj = fmaf((float)(BB - 2) * mj, mj, sj);
        float dm = 0.5f * (mi - mj);
        float between = dm * dm * pc;
        float denom = between + wi + wj;
        float x = between / denom;
        if (!(x >= 1e-37f)) x = 1e-37f;       // also catches NaN
        x = fminf(x, 1.0f - 1e-5f);
        lv[q] = x;
    }

    // ---- top-d of x (betainc monotone in x for fixed a,b) ----
    const int d = *dptr;
    float myx = 0.004f;
    float lm = lv[0];
#pragma unroll
    for (int q = 1; q < 8; ++q) lm = fmaxf(lm, lv[q]);

    for (int r = 0; r < d; ++r) {
        float gm = lm;
#pragma unroll
        for (int off = 1; off < 64; off <<= 1)
            gm = fmaxf(gm, __shfl_xor(gm, off));
        unsigned long long msk = __ballot(lm == gm);
        int winner = __ffsll((unsigned long long)msk) - 1;
        if (lane == r) myx = gm;
        if (lane == winner) {
            bool done = false;
#pragma unroll
            for (int q = 0; q < 8; ++q)
                if (!done && lv[q] == gm) { lv[q] = -1.0f; done = true; }
            lm = lv[0];
#pragma unroll
            for (int q = 1; q < 8; ++q) lm = fmaxf(lm, lv[q]);
        }
    }

    // ---- d parallel betainc evals: exact finite series for integer dof ----
    float x  = myx;
    float u  = 1.0f - x;
    float sx = sqrtf(x);
    int nu = (int)(d2 + 0.5f);
    float L;
    if (nu >= 1 && nu <= 4094 && fabsf(d2 - (float)nu) < 1e-3f) {
        float u2 = u * u;
        if (nu & 1) {
            int terms = (nu - 1) >> 1;
            float S = 0.f;
            if (terms > 0) {
                float S0 = 0.f, S1 = 0.f, p0 = 1.f, p1 = u;
                int jj = 0;
                for (; jj + 1 < terms; jj += 2) {
                    S0 = fmaf(tab_o.v[jj],     p0, S0);
                    S1 = fmaf(tab_o.v[jj + 1], p1, S1);
                    p0 *= u2; p1 *= u2;
                }
                if (jj < terms) S0 = fmaf(tab_o.v[jj], p0, S0);
                S = S0 + S1;
            }
            float theta = asinf(fminf(sx, 1.0f));
            float A = 0.636619772367581343f * (theta + sx * sqrtf(u) * S);
            L = logf(fminf(A, 1.0f));
        } else {
            int terms = nu >> 1;
            float S0 = 0.f, S1 = 0.f, p0 = 1.f, p1 = u;
            int jj = 0;
            for (; jj + 1 < terms; jj += 2) {
                S0 = fmaf(tab_e.v[jj],     p0, S0);
                S1 = fmaf(tab_e.v[jj + 1], p1, S1);
                p0 *= u2; p1 *= u2;
            }
            if (jj < terms) S0 = fmaf(tab_e.v[jj], p0, S0);
            float A = sx * (S0 + S1);
            L = logf(fminf(A, 1.0f));
        }
    } else {
        const float a = 0.5f;
        const float lg = lgammaf(a + b) - lgammaf(b) - 0.57236494f;
        const float xsplit = (a + 1.0f) / (a + b + 2.0f);
        bool  brA = x < xsplit;
        float al  = brA ? a : b;
        float be  = brA ? b : a;
        float xx  = brA ? x : u;
        float cf  = betacf_fast(al, be, xx);
        float lbt = lg + 0.5f * logf(x) + b * logf(u);
        if (brA) {
            L = lbt + logf(2.0f * fmaxf(cf, 1e-30f));
        } else {
            float tt = expf(lbt) * cf / b;
            tt = fminf(tt, 0.99999988f);
            L = log1pf(-tt);
        }
    }

    float val = (lane < d) ? L : 0.0f;
#pragma unroll
    for (int off = 1; off < 64; off <<= 1) val += __shfl_xor(val, off);

    // per-pair result -> pres[p]; last-arriving wave does deterministic sum
    unsigned old = 0u;
    if (lane == 0) {
        pres[p] = val;
        __threadfence();
        old = __hip_atomic_fetch_add(&ctrs[1], 1u, __ATOMIC_ACQ_REL,
                                     __HIP_MEMORY_SCOPE_AGENT);
    }
    old = __shfl(old, 0);
    if (old == PAIRS - 1) {
        __threadfence();
        float s = 0.f;
#pragma unroll
        for (int q = 0; q < 8; ++q) {
            int idx = q * 64 + lane;
            if (idx < PAIRS)
                s += __hip_atomic_load(&pres[idx], __ATOMIC_ACQUIRE,
                                       __HIP_MEMORY_SCOPE_AGENT);
        }
#pragma unroll
        for (int off = 1; off < 64; off <<= 1) s += __shfl_xor(s, off);
        if (lane == 0) out[0] = -s;
    }
}

// ---------------------------------------------------------------------------
extern "C" void kernel_launch(void* const* d_in, const int* in_sizes, int n_in,
                              void* d_out, int out_size, void* d_ws, size_t ws_size,
                              hipStream_t stream)
{
    const float* hidden  = (const float*)d_in[0];
    const float* cluster = (const float*)d_in[1];
    const int*   dptr    = (const int*)d_in[2];

    float*    part_m = (float*)d_ws;                     // [NBB][KK][HH]
    float*    part_s = part_m + (size_t)NBB * KK * HH;   // [NBB][KK][HH]
    float*    pcol   = part_s + (size_t)NBB * KK * HH;   // [NBB][KK]
    float*    pres   = pcol + NBB * KK;                  // [PAIRS]
    unsigned* ctrs   = (unsigned*)(pres + PAIRS);        // [2]

    hipMemsetAsync(ctrs, 0, 2 * sizeof(unsigned), stream);
    fused_kernel<<<GRID, 256, 0, stream>>>(hidden, cluster,
                                           part_m, part_s, pcol, pres,
                                           ctrs, dptr, (float*)d_out);
}

// Round 7
// 95.422 us; speedup vs baseline: 1.7006x; 1.5960x over previous
//
#include <hip/hip_runtime.h>
#include <math.h>

#define BB 4096
#define HH 512
#define KK 32
#define PAIRS ((KK * (KK - 1)) / 2)   // 496

constexpr int TH  = 16;          // h-values per stage1 block
constexpr int NBB = 16;          // B-chunks
constexpr int BC  = BB / NBB;    // 256 rows per block
constexpr int SUB = 64;          // rows staged in LDS at a time
constexpr int GK  = 16;          // row-groups (2 k per thread)
constexpr int RP  = 17;          // red row stride in floats (16 + 1 pad)

// ws layout (floats): part_m[NBB][KK][HH], part_s[NBB][KK][HH],
//                     pcol[NBB][KK], ctl[2] = {accum(float), counter(uint)}

// ---------------------------------------------------------------------------
// Exact t-CDF series coefficients (A&S 26.7.3/4), compile-time tables.
//   even nu: A = sqrt(x) * sum ce[j]*(1-x)^j,         ce[j]=prod (2i-1)/(2i)
//   odd  nu: A = 2/pi*(theta + sqrt(x(1-x))*sum co[j]*(1-x)^j),
//            co[j]=prod (2i)/(2i+1), theta = asin(sqrt(x))
// ---------------------------------------------------------------------------
struct TabE {
    float v[2048];
    constexpr TabE() : v{} {
        double c = 1.0; v[0] = 1.0f;
        for (int j = 1; j < 2048; ++j) { c *= (2.0*j - 1.0) / (2.0*j); v[j] = (float)c; }
    }
};
struct TabO {
    float v[2048];
    constexpr TabO() : v{} {
        double c = 1.0; v[0] = 1.0f;
        for (int j = 1; j < 2048; ++j) { c *= (2.0*j) / (2.0*j + 1.0); v[j] = (float)c; }
    }
};
__device__ constexpr TabE tab_e{};
__device__ constexpr TabO tab_o{};

// ---------------------------------------------------------------------------
// Stage 1: per-chunk partials, no atomics, no zero-init.
// 2 k per thread: g = t>>4 row-group, tx = t&15, k in {tx, tx+16}.
// Squares recomputed in-register (no hid2 LDS array).
// ---------------------------------------------------------------------------
__global__ __launch_bounds__(256) void stage1_kernel(
    const float* __restrict__ hidden, const float* __restrict__ cluster,
    float* __restrict__ part_m, float* __restrict__ part_s,
    float* __restrict__ pcol, float* __restrict__ ctl)
{
    __shared__ float hid_s[SUB * TH];      // 4 KB
    __shared__ float clu_s[SUB * KK];      // 8 KB
    __shared__ float red  [GK * KK * RP];  // 34816 B
    __shared__ float cred [GK * KK];       // 2 KB

    const int t  = threadIdx.x;
    const int g  = t >> 4;         // 0..15 row-group
    const int tx = t & 15;         // k base
    const int h0 = blockIdx.x * TH;
    const int c  = blockIdx.y;
    const int bchunk = c * BC;

    if (blockIdx.x == 0 && c == 0 && t == 0) {
        ctl[0] = 0.0f;
        ((unsigned*)ctl)[1] = 0u;
    }

    float am0[TH], am1[TH], as0[TH], as1[TH];
#pragma unroll
    for (int i = 0; i < TH; ++i) { am0[i]=0.f; am1[i]=0.f; as0[i]=0.f; as1[i]=0.f; }
    float cs0 = 0.f, cs1 = 0.f;

    const float4* hid4 = (const float4*)hidden;
    const float4* clu4 = (const float4*)cluster;

    for (int sub = 0; sub < BC; sub += SUB) {
        const int b0 = bchunk + sub;
        {   // hidden tile: 64 rows x 16 cols = 256 float4, one per thread
            int r = t >> 2, q = t & 3;
            ((float4*)hid_s)[t] =
                hid4[(size_t)(b0 + r) * (HH / 4) + (h0 >> 2) + q];
        }
#pragma unroll
        for (int e = 0; e < 2; ++e) {      // cluster tile: 512 float4
            int u = t + e * 256;
            int r = u >> 3, q = u & 7;
            ((float4*)clu_s)[u] = clu4[(size_t)(b0 + r) * (KK / 4) + q];
        }
        __syncthreads();

        const float4* h4 = (const float4*)hid_s;
#pragma unroll
        for (int s = 0; s < SUB / GK; ++s) {   // 4 rows per group per tile
            int r = s * GK + g;
            float c0 = clu_s[r * KK + tx];
            float c1 = clu_s[r * KK + tx + 16];
            cs0 += c0; cs1 += c1;
            float c0q = c0 * c0, c1q = c1 * c1;
            float4 a0 = h4[r*4+0], a1 = h4[r*4+1], a2 = h4[r*4+2], a3 = h4[r*4+3];
#define DO_H(idx, val)                                              \
            { float v_ = (val); float vq_ = v_ * v_;                \
              am0[idx] = fmaf(v_,  c0,  am0[idx]);                  \
              am1[idx] = fmaf(v_,  c1,  am1[idx]);                  \
              as0[idx] = fmaf(vq_, c0q, as0[idx]);                  \
              as1[idx] = fmaf(vq_, c1q, as1[idx]); }
            DO_H(0,  a0.x) DO_H(1,  a0.y) DO_H(2,  a0.z) DO_H(3,  a0.w)
            DO_H(4,  a1.x) DO_H(5,  a1.y) DO_H(6,  a1.z) DO_H(7,  a1.w)
            DO_H(8,  a2.x) DO_H(9,  a2.y) DO_H(10, a2.z) DO_H(11, a2.w)
            DO_H(12, a3.x) DO_H(13, a3.y) DO_H(14, a3.z) DO_H(15, a3.w)
#undef DO_H
        }
        __syncthreads();
    }

    // colsum partials: cred[g][k]
    cred[g * KK + tx]      = cs0;
    cred[g * KK + tx + 16] = cs1;
    __syncthreads();
    if (blockIdx.x == 0 && t < KK) {
        float v = 0.f;
#pragma unroll
        for (int g2 = 0; g2 < GK; ++g2) v += cred[g2 * KK + t];
        pcol[c * KK + t] = v;
    }

    // cross-group reduce: pass m
#pragma unroll
    for (int h = 0; h < TH; ++h) {
        red[(g * KK + tx)      * RP + h] = am0[h];
        red[(g * KK + tx + 16) * RP + h] = am1[h];
    }
    __syncthreads();
#pragma unroll
    for (int e = 0; e < 2; ++e) {
        int u = t + e * 256;
        int k = u >> 4, h = u & 15;
        float v = 0.f;
#pragma unroll
        for (int g2 = 0; g2 < GK; ++g2) v += red[(g2 * KK + k) * RP + h];
        part_m[((size_t)c * KK + k) * HH + h0 + h] = v;
    }
    __syncthreads();
    // pass s
#pragma unroll
    for (int h = 0; h < TH; ++h) {
        red[(g * KK + tx)      * RP + h] = as0[h];
        red[(g * KK + tx + 16) * RP + h] = as1[h];
    }
    __syncthreads();
#pragma unroll
    for (int e = 0; e < 2; ++e) {
        int u = t + e * 256;
        int k = u >> 4, h = u & 15;
        float v = 0.f;
#pragma unroll
        for (int g2 = 0; g2 < GK; ++g2) v += red[(g2 * KK + k) * RP + h];
        part_s[((size_t)c * KK + k) * HH + h0 + h] = v;
    }
}

// ---------------------------------------------------------------------------
__device__ __forceinline__ float frcp(float x) {
#if __has_builtin(__builtin_amdgcn_rcpf)
    return __builtin_amdgcn_rcpf(x);
#else
    return 1.0f / x;
#endif
}
__device__ __forceinline__ float guardf(float t) {
    return (fabsf(t) < 1e-30f) ? 1e-30f : t;
}

// NR betacf fallback (only for non-integer d2 — never taken with this data)
__device__ float betacf_fast(float a, float b, float x)
{
    const float EPS = 1e-5f;
    float qab = a + b, qap = a + 1.0f, qam = a - 1.0f;
    float c = 1.0f;
    float d = frcp(guardf(1.0f - qab * x * frcp(qap)));
    float h = d;
    for (int m = 1; m <= 100; ++m) {
        float fm = (float)m, m2 = 2.0f * fm;
        float aa = fm * (b - fm) * x * frcp((qam + m2) * (a + m2));
        d = frcp(guardf(fmaf(aa, d, 1.0f)));
        c = guardf(fmaf(aa, frcp(c), 1.0f));
        h *= d * c;
        float aa2 = -(a + fm) * (qab + fm) * x * frcp((a + m2) * (qap + m2));
        d = frcp(guardf(fmaf(aa2, d, 1.0f)));
        c = guardf(fmaf(aa2, frcp(c), 1.0f));
        float del = d * c;
        h *= del;
        if (__all(fabsf(del - 1.0f) < EPS)) break;
    }
    return h;
}

// ---------------------------------------------------------------------------
// Stage 2: one block (4 waves) per pair. Waves 0-3 chunk-reduce partials and
// compute x for 128 h each; wave 0: top-d of x (betainc monotone in x) then
// d parallel EXACT t-CDF series evals, sum logs, last-block writeout.
// ---------------------------------------------------------------------------
__global__ __launch_bounds__(256) void stage2_kernel(
    const float* __restrict__ part_m, const float* __restrict__ part_s,
    const float* __restrict__ pcol, float* __restrict__ ctl,
    const int* __restrict__ dptr, float* __restrict__ out)
{
    __shared__ float xs[HH];

    const int t = threadIdx.x;
    const int w = t >> 6, lane = t & 63;
    const int p = blockIdx.x;

    int i = 0, rem = p;
    while (true) { int row = KK - 1 - i; if (rem < row) break; rem -= row; ++i; }
    const int j = i + 1 + rem;

    float ci = 0.f, cj = 0.f;
#pragma unroll
    for (int cc = 0; cc < NBB; ++cc) {
        ci += pcol[cc * KK + i];
        cj += pcol[cc * KK + j];
    }
    ci = roundf(ci); cj = roundf(cj);
    const float pc = ci + cj;
    float d2 = pc - 2.0f;
    if (d2 == 0.0f) d2 = 1e-5f;
    const float b = 0.5f * d2;

#pragma unroll
    for (int q = 0; q < 2; ++q) {
        int h = w * 128 + q * 64 + lane;
        float mi = 0.f, mj = 0.f, si = 0.f, sj = 0.f;
#pragma unroll
        for (int cc = 0; cc < NBB; ++cc) {
            size_t base = (size_t)cc * KK * HH;
            mi += part_m[base + (size_t)i * HH + h];
            mj += part_m[base + (size_t)j * HH + h];
            si += part_s[base + (size_t)i * HH + h];
            sj += part_s[base + (size_t)j * HH + h];
        }
        float wi = fmaf((float)(BB - 2) * mi, mi, si);
        float wj = fmaf((float)(BB - 2) * mj, mj, sj);
        float dm = 0.5f * (mi - mj);
        float between = dm * dm * pc;
        float denom = between + wi + wj;
        float x = between / denom;
        if (!(x >= 1e-37f)) x = 1e-37f;       // also catches NaN
        x = fminf(x, 1.0f - 1e-5f);
        xs[h] = x;
    }
    __syncthreads();
    if (w != 0) return;

    // ---- wave 0: top-d of x over 512 values (8/lane) ----
    float lv[8];
#pragma unroll
    for (int q = 0; q < 8; ++q) lv[q] = xs[q * 64 + lane];

    const int d = *dptr;
    float myx = 0.004f;
    float lm = lv[0];
#pragma unroll
    for (int q = 1; q < 8; ++q) lm = fmaxf(lm, lv[q]);

    for (int r = 0; r < d; ++r) {
        float gm = lm;
#pragma unroll
        for (int off = 1; off < 64; off <<= 1)
            gm = fmaxf(gm, __shfl_xor(gm, off));
        unsigned long long msk = __ballot(lm == gm);
        int winner = __ffsll((unsigned long long)msk) - 1;
        if (lane == r) myx = gm;
        if (lane == winner) {
            bool done = false;
#pragma unroll
            for (int q = 0; q < 8; ++q)
                if (!done && lv[q] == gm) { lv[q] = -1.0f; done = true; }
            lm = lv[0];
#pragma unroll
            for (int q = 1; q < 8; ++q) lm = fmaxf(lm, lv[q]);
        }
    }

    // ---- d parallel betainc evals: exact finite series for integer dof ----
    float x  = myx;
    float u  = 1.0f - x;
    float sx = sqrtf(x);
    int nu = (int)(d2 + 0.5f);
    float L;
    if (nu >= 1 && nu <= 4094 && fabsf(d2 - (float)nu) < 1e-3f) {
        float u2 = u * u;
        if (nu & 1) {
            int terms = (nu - 1) >> 1;
            float S = 0.f;
            if (terms > 0) {
                float S0 = 0.f, S1 = 0.f, p0 = 1.f, p1 = u;
                int jj = 0;
                for (; jj + 1 < terms; jj += 2) {
                    S0 = fmaf(tab_o.v[jj],     p0, S0);
                    S1 = fmaf(tab_o.v[jj + 1], p1, S1);
                    p0 *= u2; p1 *= u2;
                }
                if (jj < terms) S0 = fmaf(tab_o.v[jj], p0, S0);
                S = S0 + S1;
            }
            float theta = asinf(fminf(sx, 1.0f));
            float A = 0.636619772367581343f * (theta + sx * sqrtf(u) * S);
            L = logf(fminf(A, 1.0f));
        } else {
            int terms = nu >> 1;
            float S0 = 0.f, S1 = 0.f, p0 = 1.f, p1 = u;
            int jj = 0;
            for (; jj + 1 < terms; jj += 2) {
                S0 = fmaf(tab_e.v[jj],     p0, S0);
                S1 = fmaf(tab_e.v[jj + 1], p1, S1);
                p0 *= u2; p1 *= u2;
            }
            if (jj < terms) S0 = fmaf(tab_e.v[jj], p0, S0);
            float A = sx * (S0 + S1);
            L = logf(fminf(A, 1.0f));
        }
    } else {
        const float a = 0.5f;
        const float lg = lgammaf(a + b) - lgammaf(b) - 0.57236494f;
        const float xsplit = (a + 1.0f) / (a + b + 2.0f);
        bool  brA = x < xsplit;
        float al  = brA ? a : b;
        float be  = brA ? b : a;
        float xx  = brA ? x : u;
        float cf  = betacf_fast(al, be, xx);
        float lbt = lg + 0.5f * logf(x) + b * logf(u);
        if (brA) {
            L = lbt + logf(2.0f * fmaxf(cf, 1e-30f));
        } else {
            float tt = expf(lbt) * cf / b;
            tt = fminf(tt, 0.99999988f);
            L = log1pf(-tt);
        }
    }

    float val = (lane < d) ? L : 0.0f;
#pragma unroll
    for (int off = 1; off < 64; off <<= 1) val += __shfl_xor(val, off);

    if (lane == 0) {
        atomicAdd(&ctl[0], -val);
        __threadfence();
        unsigned old = atomicAdd((unsigned*)ctl + 1, 1u);
        if (old == PAIRS - 1) {
            out[0] = atomicAdd(&ctl[0], 0.0f);   // atomic read of final sum
        }
    }
}

// ---------------------------------------------------------------------------
extern "C" void kernel_launch(void* const* d_in, const int* in_sizes, int n_in,
                              void* d_out, int out_size, void* d_ws, size_t ws_size,
                              hipStream_t stream)
{
    const float* hidden  = (const float*)d_in[0];
    const float* cluster = (const float*)d_in[1];
    const int*   dptr    = (const int*)d_in[2];

    float* part_m = (float*)d_ws;                    // [NBB][KK][HH]
    float* part_s = part_m + (size_t)NBB * KK * HH;  // [NBB][KK][HH]
    float* pcol   = part_s + (size_t)NBB * KK * HH;  // [NBB][KK]
    float* ctl    = pcol + NBB * KK;                 // accum, counter

    dim3 g1(HH / TH, NBB);
    stage1_kernel<<<g1, 256, 0, stream>>>(hidden, cluster,
                                          part_m, part_s, pcol, ctl);
    stage2_kernel<<<PAIRS, 256, 0, stream>>>(part_m, part_s, pcol, ctl,
                                             dptr, (float*)d_out);
}